// Round 1
// baseline (291.202 us; speedup 1.0000x reference)
//
#include <hip/hip_runtime.h>
#include <hip/hip_fp16.h>
#include <cmath>

#define HEADS 4
#define CH 64
#define HC 256
#define NEG 0.2f

typedef __attribute__((ext_vector_type(8))) short short8;
typedef __attribute__((ext_vector_type(4))) float f32x4;
typedef __fp16 half2_t __attribute__((ext_vector_type(2)));

__device__ __forceinline__ float leaky(float v){ return v > 0.f ? v : NEG * v; }

__device__ __forceinline__ short bf16_rne(float f){
    unsigned u = __float_as_uint(f);
    unsigned r = u + 0x7fffu + ((u >> 16) & 1u);
    return (short)(r >> 16);
}
__device__ __forceinline__ float bf16_to_f(short s){
    return __uint_as_float(((unsigned)(unsigned short)s) << 16);
}
__device__ __forceinline__ half2_t bc16(unsigned u){ return __builtin_bit_cast(half2_t, u); }
__device__ __forceinline__ unsigned packh2(float a, float b){
    __half ha = __float2half(a), hb = __float2half(b);   // RNE
    return (unsigned)__builtin_bit_cast(unsigned short, ha)
         | ((unsigned)__builtin_bit_cast(unsigned short, hb) << 16);
}

// block-wide exclusive scan of one int per thread (256 threads)
__device__ __forceinline__ int block_excl_scan(int v, int* ws4){
    int tid = threadIdx.x, lane = tid & 63, wv = tid >> 6;
    int incl = v;
    #pragma unroll
    for (int off = 1; off < 64; off <<= 1){
        int t = __shfl_up(incl, off);
        if (lane >= off) incl += t;
    }
    if (lane == 63) ws4[wv] = incl;
    __syncthreads();
    int add = 0;
    for (int w = 0; w < wv; ++w) add += ws4[w];
    return incl - v + add;
}

// ---------------- prep (+ edge histogram tail) ----------------

__global__ __launch_bounds__(256) void prep_hist_kernel(
    const float* __restrict__ W1, const float* __restrict__ W2,
    const float* __restrict__ Ws1, const float* __restrict__ bs1,
    const float* __restrict__ donor,
    short* __restrict__ w1hi, short* __restrict__ w2hi,
    short* __restrict__ s1hi, short* __restrict__ s1lo,
    float* __restrict__ d1p,
    const int* __restrict__ ei, int E, int N, int NB, int* __restrict__ bucket_cnt)
{
    if ((int)blockIdx.x < 256){
        int t = blockIdx.x * 256 + threadIdx.x;
        int T = 256 * 256;
        for (int i = t; i < 256 * 40; i += T){                  // W1 bf16: [n=256][k pitch 40], K=27
            int n = i / 40, k = i % 40;
            w1hi[i] = bf16_rne((k < 27) ? W1[(size_t)k * HC + n] : 0.f);
        }
        for (int i = t; i < 256 * 72; i += T){                  // W2 bf16: [n=256][k pitch 72], K=64
            int n = i / 72, k = i % 72;
            w2hi[i] = bf16_rne((k < 64) ? W2[(size_t)k * HC + n] : 0.f);
        }
        for (int i = t; i < 64 * 72; i += T){                   // Ws1 bf16x3 (scorer)
            int n = i / 72, k = i % 72;
            float v = (k < 64) ? Ws1[(size_t)k * 64 + n] : 0.f;
            short hi = bf16_rne(v);
            s1hi[i] = hi; s1lo[i] = bf16_rne(v - bf16_to_f(hi));
        }
        if (t < 64){
            float s = bs1[t];
            for (int k = 0; k < 32; ++k) s = fmaf(donor[k], Ws1[(size_t)(64 + k) * 64 + t], s);
            d1p[t] = s;
        }
    } else {
        __shared__ int lh[256];
        int tid = threadIdx.x;
        int ET = E + N;
        int ebase = ((int)blockIdx.x - 256) * 2048;
        lh[tid] = 0;
        __syncthreads();
        #pragma unroll
        for (int j = 0; j < 8; ++j){
            int e = ebase + j * 256 + tid;
            if (e < ET){
                int d = (e < E) ? ei[E + e] : (e - E);
                atomicAdd(&lh[d >> 8], 1);
            }
        }
        __syncthreads();
        if (tid < NB && lh[tid]) atomicAdd(&bucket_cnt[tid], lh[tid]);
    }
}

// ---------------- coarse scatter (self-scan, packed uint32 pairs) ----------------

__global__ __launch_bounds__(256) void coarse_scatter_kernel(
    const int* __restrict__ ei, int E, int N, int NB,
    const int* __restrict__ bucket_cnt, int* __restrict__ bucket_cursor,
    unsigned* __restrict__ pairs)
{
    __shared__ int ws4[4];
    __shared__ int gbase[256];
    __shared__ int lh[256];
    __shared__ int gb[256];
    int tid = threadIdx.x;
    int ET = E + N;
    {
        int v = (tid < NB) ? bucket_cnt[tid] : 0;
        gbase[tid] = block_excl_scan(v, ws4);
    }
    lh[tid] = 0;
    __syncthreads();
    int ebase = blockIdx.x * 2048;
    int d[8], s[8], r[8];
    #pragma unroll
    for (int j = 0; j < 8; ++j){
        int e = ebase + j * 256 + tid;
        d[j] = -1;
        if (e < ET){
            if (e < E){ s[j] = ei[e]; d[j] = ei[E + e]; } else { s[j] = d[j] = e - E; }
            r[j] = atomicAdd(&lh[d[j] >> 8], 1);
        }
    }
    __syncthreads();
    if (tid < NB && lh[tid]) gb[tid] = gbase[tid] + atomicAdd(&bucket_cursor[tid], lh[tid]);
    __syncthreads();
    #pragma unroll
    for (int j = 0; j < 8; ++j){
        if (d[j] >= 0)
            pairs[gb[d[j] >> 8] + r[j]] = ((unsigned)d[j] << 16) | (unsigned)s[j];
    }
}

// ---------------- fine sort body (self-scan, block-local writes) ----------------

__device__ __forceinline__ void fine_sort_body(
    int b, const unsigned* __restrict__ pairs, const int* __restrict__ bucket_cnt, int NB,
    int* __restrict__ colsrc, int* __restrict__ rowptr, int N, int ET)
{
    __shared__ int ws4f[4];
    __shared__ int sb[257];
    __shared__ int hist[256];
    __shared__ int cur[256];
    int tid = threadIdx.x;
    {
        int v = (tid < NB) ? bucket_cnt[tid] : 0;
        int excl = block_excl_scan(v, ws4f);
        sb[tid] = excl;
        if (tid == 255) sb[256] = excl + v;
    }
    hist[tid] = 0;
    __syncthreads();
    int base = sb[b], endb = sb[b + 1];
    int cnt = endb - base;
    int d0 = b << 8;
    for (int i = tid; i < cnt; i += 256){
        unsigned p = pairs[base + i];
        atomicAdd(&hist[(int)(p >> 16) - d0], 1);
    }
    __syncthreads();
    int v = hist[tid];
    int excl = block_excl_scan(v, ws4f);
    cur[tid] = excl;
    if (d0 + tid < N) rowptr[d0 + tid] = base + excl;
    if (b == 0 && tid == 0) rowptr[N] = ET;
    __syncthreads();
    for (int i = tid; i < cnt; i += 256){
        unsigned p = pairs[base + i];
        int r = atomicAdd(&cur[(int)(p >> 16) - d0], 1);
        colsrc[base + r] = (int)(p & 0xFFFFu);
    }
}

// ---------------- MFMA node transform (device body) ----------------
// X3: bf16x3 A*B split. DIRECT: FIN==64, read A-fragments straight from global
// (contiguous 32B/lane, wave covers 16 consecutive rows) — no xl staging.

template<int FIN, int KSTEPS, int NT, bool X3, bool DIRECT>
__device__ __forceinline__ void transform_body(
    int bx, int by,
    const float* __restrict__ xin, const short* __restrict__ whi, const short* __restrict__ wlo,
    const float* __restrict__ a_src, const float* __restrict__ a_dst,
    __half* __restrict__ h, float* __restrict__ asrc, float* __restrict__ adst, int N)
{
    constexpr int KP = KSTEPS * 32;
    constexpr int XP = KP + 4;
    constexpr int WP = KP + 8;
    constexpr int NCOL = NT * 16;
    __shared__ float xl[DIRECT ? 8 : 64 * XP];
    __shared__ short wt_hi[NCOL * WP];
    __shared__ short wt_lo[X3 ? NCOL * WP : 8];

    const int tid = threadIdx.x;
    const int n0 = bx * 64;
    const int c0 = by * NCOL;

    const int wv = tid >> 6, lane = tid & 63;
    const int quad = lane >> 4, ln = lane & 15;
    const int myrow = wv * 16 + ln;

    float fdir[DIRECT ? KSTEPS * 8 : 1];
    if (DIRECT){
        int n = n0 + myrow;
        #pragma unroll
        for (int ks = 0; ks < KSTEPS; ++ks){
            float4 f0 = make_float4(0.f, 0.f, 0.f, 0.f), f1 = f0;
            if (n < N){
                const float* ap = xin + (size_t)n * FIN + ks * 32 + quad * 8;
                f0 = *(const float4*)ap;
                f1 = *(const float4*)(ap + 4);
            }
            fdir[ks*8+0]=f0.x; fdir[ks*8+1]=f0.y; fdir[ks*8+2]=f0.z; fdir[ks*8+3]=f0.w;
            fdir[ks*8+4]=f1.x; fdir[ks*8+5]=f1.y; fdir[ks*8+6]=f1.z; fdir[ks*8+7]=f1.w;
        }
    } else {
        for (int t = tid; t < 64 * KP; t += 256) {
            int row = t / KP, k = t % KP;
            int n = n0 + row;
            float v = 0.f;
            if (n < N && k < FIN) v = xin[(size_t)n * FIN + k];
            xl[row * XP + k] = v;
        }
    }
    {
        const short8* ghi = (const short8*)(whi + (size_t)c0 * WP);
        short8* lhi = (short8*)wt_hi;
        for (int t = tid; t < NCOL * WP / 8; t += 256) lhi[t] = ghi[t];
        if (X3){
            const short8* glo = (const short8*)(wlo + (size_t)c0 * WP);
            short8* llo = (short8*)wt_lo;
            for (int t = tid; t < NCOL * WP / 8; t += 256) llo[t] = glo[t];
        }
    }
    __syncthreads();

    f32x4 acc[NT];
    #pragma unroll
    for (int i = 0; i < NT; ++i) acc[i] = (f32x4){0.f, 0.f, 0.f, 0.f};

    #pragma unroll
    for (int ks = 0; ks < KSTEPS; ++ks) {
        const int k0 = ks * 32 + quad * 8;
        float fa[8];
        if (DIRECT){
            #pragma unroll
            for (int e = 0; e < 8; ++e) fa[e] = fdir[ks * 8 + e];
        } else {
            const float* ap = xl + myrow * XP + k0;
            float4 f0 = *(const float4*)ap;
            float4 f1 = *(const float4*)(ap + 4);
            fa[0]=f0.x; fa[1]=f0.y; fa[2]=f0.z; fa[3]=f0.w;
            fa[4]=f1.x; fa[5]=f1.y; fa[6]=f1.z; fa[7]=f1.w;
        }
        short8 ahi, alo;
        #pragma unroll
        for (int e = 0; e < 8; ++e) {
            short hi = bf16_rne(fa[e]);
            ahi[e] = hi;
            alo[e] = bf16_rne(fa[e] - bf16_to_f(hi));
        }
        #pragma unroll
        for (int nt = 0; nt < NT; ++nt) {
            short8 bhi = *(const short8*)(wt_hi + (nt * 16 + ln) * WP + k0);
            acc[nt] = __builtin_amdgcn_mfma_f32_16x16x32_bf16(ahi, bhi, acc[nt], 0, 0, 0);
            acc[nt] = __builtin_amdgcn_mfma_f32_16x16x32_bf16(alo, bhi, acc[nt], 0, 0, 0);
            if (X3){
                short8 blo = *(const short8*)(wt_lo + (nt * 16 + ln) * WP + k0);
                acc[nt] = __builtin_amdgcn_mfma_f32_16x16x32_bf16(ahi, blo, acc[nt], 0, 0, 0);
            }
        }
    }

    #pragma unroll
    for (int r = 0; r < 4; ++r) {
        int n = n0 + wv * 16 + quad * 4 + r;
        if (n < N) {
            if (NT == 16) {
                #pragma unroll
                for (int q = 0; q < 4; ++q) {
                    uint2 u;
                    u.x = packh2(acc[q][r],     acc[q + 4][r]);
                    u.y = packh2(acc[q + 8][r], acc[q + 12][r]);
                    *(uint2*)((char*)h + (size_t)n * 512 + (q * 16 + ln) * 8) = u;
                }
            } else {
                #pragma unroll
                for (int q = 0; q < 4; ++q) {
                    unsigned u = packh2(acc[q][r], acc[q + 4][r]);
                    *(unsigned*)((char*)h + (size_t)n * 512 + (q * 16 + ln) * 8 + ((c0 >> 6) << 1)) = u;
                }
            }
        }
    }

    float aS[NT], aD[NT];
    #pragma unroll
    for (int nt = 0; nt < NT; ++nt) {
        aS[nt] = a_src[c0 + nt * 16 + ln];
        aD[nt] = a_dst[c0 + nt * 16 + ln];
    }
    #pragma unroll
    for (int hl = 0; hl < NT / 4; ++hl) {
        #pragma unroll
        for (int r = 0; r < 4; ++r) {
            float ps = 0.f, pd = 0.f;
            #pragma unroll
            for (int i = 0; i < 4; ++i) {
                ps = fmaf(acc[hl * 4 + i][r], aS[hl * 4 + i], ps);
                pd = fmaf(acc[hl * 4 + i][r], aD[hl * 4 + i], pd);
            }
            #pragma unroll
            for (int off = 1; off < 16; off <<= 1) {
                ps += __shfl_xor(ps, off);
                pd += __shfl_xor(pd, off);
            }
            if (ln == 0) {
                int n = n0 + wv * 16 + quad * 4 + r;
                if (n < N) {
                    int hg = c0 / 64 + hl;
                    asrc[n * 4 + hg] = ps;
                    adst[n * 4 + hg] = pd;
                }
            }
        }
    }
}

// transform1 (bf16x2, LDS-staged x: FIN=27) fused with fine-sort tail blocks
__global__ __launch_bounds__(256) void transform1_fine_kernel(
    const float* __restrict__ xin, const short* __restrict__ whi,
    const float* __restrict__ a_src, const float* __restrict__ a_dst,
    __half* __restrict__ h, float* __restrict__ asrc, float* __restrict__ adst, int N,
    int nblk, const unsigned* __restrict__ pairs, const int* __restrict__ bucket_cnt, int NB,
    int* __restrict__ colsrc, int* __restrict__ rowptr, int ET)
{
    if ((int)blockIdx.x < nblk) {
        transform_body<27, 1, 16, false, false>(blockIdx.x, 0, xin, whi, nullptr,
                                                a_src, a_dst, h, asrc, adst, N);
    } else {
        fine_sort_body(blockIdx.x - nblk, pairs, bucket_cnt, NB, colsrc, rowptr, N, ET);
    }
}

// transform2: NT=16 single pass, bf16x2, DIRECT global A reads (36.9 KB LDS)
__global__ __launch_bounds__(256) void transform2_kernel(
    const float* __restrict__ xin, const short* __restrict__ whi,
    const float* __restrict__ a_src, const float* __restrict__ a_dst,
    __half* __restrict__ h, float* __restrict__ asrc, float* __restrict__ adst, int N)
{
    transform_body<64, 2, 16, false, true>(blockIdx.x, 0, xin, whi, nullptr,
                                           a_src, a_dst, h, asrc, adst, N);
}

// ---------------- per-dst aggregation: 2 nodes/wave, shfl-broadcast sweep ----------------
// deg<=32 (>99.9% of nodes, Poisson(16)+self-loop): specialized 4-wide unrolled
// sweep — 4 independent uint4 gathers in flight per lane before consumption,
// fdot2 chain split across 2 accumulator pairs. Attacks gather latency (VALUBusy
// was 24%, BW 42% => latency-bound, not BW-bound).

__global__ __launch_bounds__(256) void aggregate_kernel(
    const int* __restrict__ rowptr, const int* __restrict__ colsrc,
    const __half* __restrict__ h, const float* __restrict__ asrc,
    const float* __restrict__ adst, const float* __restrict__ bias,
    float* __restrict__ hout, int N)
{
    int tid = threadIdx.x;
    int grp = tid >> 5;
    int lane32 = tid & 31;
    int n = blockIdx.x * 8 + grp;
    if (n >= N) return;
    int start = rowptr[n], end = rowptr[n + 1];
    int deg = end - start;
    const float4 ad = *(const float4*)(adst + (size_t)n * 4);

    int src0 = 0;
    float e0 = -1e30f, e1 = -1e30f, e2 = -1e30f, e3 = -1e30f;
    bool v0 = lane32 < deg;
    if (v0){
        src0 = colsrc[start + lane32];
        float4 as = *(const float4*)(asrc + (size_t)src0 * 4);
        e0 = leaky(as.x + ad.x); e1 = leaky(as.y + ad.y);
        e2 = leaky(as.z + ad.z); e3 = leaky(as.w + ad.w);
    }

    float accA = 0.f, accB = 0.f;
    const int boff = lane32 * 16;

    if (deg <= 32){
        float m0 = e0, m1 = e1, m2 = e2, m3 = e3;
        #pragma unroll
        for (int off = 1; off < 32; off <<= 1){
            m0 = fmaxf(m0, __shfl_xor(m0, off));
            m1 = fmaxf(m1, __shfl_xor(m1, off));
            m2 = fmaxf(m2, __shfl_xor(m2, off));
            m3 = fmaxf(m3, __shfl_xor(m3, off));
        }
        float p0 = __expf(e0 - m0);
        float p1 = __expf(e1 - m1);
        float p2 = __expf(e2 - m2);
        float p3 = __expf(e3 - m3);
        float t0 = p0, t1 = p1, t2 = p2, t3 = p3;
        #pragma unroll
        for (int off = 1; off < 32; off <<= 1){
            t0 += __shfl_xor(t0, off);
            t1 += __shfl_xor(t1, off);
            t2 += __shfl_xor(t2, off);
            t3 += __shfl_xor(t3, off);
        }
        half2_t q01 = __builtin_amdgcn_cvt_pkrtz(p0 / t0, p1 / t1);
        half2_t q23 = __builtin_amdgcn_cvt_pkrtz(p2 / t2, p3 / t3);
        int wx = (int)__builtin_bit_cast(unsigned, q01);
        int wy = (int)__builtin_bit_cast(unsigned, q23);
        int offv = v0 ? src0 * (HC * 2) : 0;

        float accA1 = 0.f, accB1 = 0.f;
        int j = 0;
        for (; j + 4 <= deg; j += 4){
            int o0 = __shfl(offv, j, 32);
            int o1 = __shfl(offv, j + 1, 32);
            int o2 = __shfl(offv, j + 2, 32);
            int o3 = __shfl(offv, j + 3, 32);
            uint4 h0 = *(const uint4*)((const char*)h + o0 + boff);
            uint4 h1 = *(const uint4*)((const char*)h + o1 + boff);
            uint4 h2 = *(const uint4*)((const char*)h + o2 + boff);
            uint4 h3 = *(const uint4*)((const char*)h + o3 + boff);
            unsigned a0 = (unsigned)__shfl(wx, j, 32),     c0 = (unsigned)__shfl(wy, j, 32);
            unsigned a1 = (unsigned)__shfl(wx, j + 1, 32), c1 = (unsigned)__shfl(wy, j + 1, 32);
            unsigned a2 = (unsigned)__shfl(wx, j + 2, 32), c2 = (unsigned)__shfl(wy, j + 2, 32);
            unsigned a3 = (unsigned)__shfl(wx, j + 3, 32), c3 = (unsigned)__shfl(wy, j + 3, 32);
            accA  = __builtin_amdgcn_fdot2(bc16(h0.x), bc16(a0), accA,  false);
            accA  = __builtin_amdgcn_fdot2(bc16(h0.y), bc16(c0), accA,  false);
            accB  = __builtin_amdgcn_fdot2(bc16(h0.z), bc16(a0), accB,  false);
            accB  = __builtin_amdgcn_fdot2(bc16(h0.w), bc16(c0), accB,  false);
            accA1 = __builtin_amdgcn_fdot2(bc16(h1.x), bc16(a1), accA1, false);
            accA1 = __builtin_amdgcn_fdot2(bc16(h1.y), bc16(c1), accA1, false);
            accB1 = __builtin_amdgcn_fdot2(bc16(h1.z), bc16(a1), accB1, false);
            accB1 = __builtin_amdgcn_fdot2(bc16(h1.w), bc16(c1), accB1, false);
            accA  = __builtin_amdgcn_fdot2(bc16(h2.x), bc16(a2), accA,  false);
            accA  = __builtin_amdgcn_fdot2(bc16(h2.y), bc16(c2), accA,  false);
            accB  = __builtin_amdgcn_fdot2(bc16(h2.z), bc16(a2), accB,  false);
            accB  = __builtin_amdgcn_fdot2(bc16(h2.w), bc16(c2), accB,  false);
            accA1 = __builtin_amdgcn_fdot2(bc16(h3.x), bc16(a3), accA1, false);
            accA1 = __builtin_amdgcn_fdot2(bc16(h3.y), bc16(c3), accA1, false);
            accB1 = __builtin_amdgcn_fdot2(bc16(h3.z), bc16(a3), accB1, false);
            accB1 = __builtin_amdgcn_fdot2(bc16(h3.w), bc16(c3), accB1, false);
        }
        if (j + 2 <= deg){
            int o0 = __shfl(offv, j, 32);
            int o1 = __shfl(offv, j + 1, 32);
            uint4 h0 = *(const uint4*)((const char*)h + o0 + boff);
            uint4 h1 = *(const uint4*)((const char*)h + o1 + boff);
            unsigned a0 = (unsigned)__shfl(wx, j, 32),     c0 = (unsigned)__shfl(wy, j, 32);
            unsigned a1 = (unsigned)__shfl(wx, j + 1, 32), c1 = (unsigned)__shfl(wy, j + 1, 32);
            accA  = __builtin_amdgcn_fdot2(bc16(h0.x), bc16(a0), accA,  false);
            accA  = __builtin_amdgcn_fdot2(bc16(h0.y), bc16(c0), accA,  false);
            accB  = __builtin_amdgcn_fdot2(bc16(h0.z), bc16(a0), accB,  false);
            accB  = __builtin_amdgcn_fdot2(bc16(h0.w), bc16(c0), accB,  false);
            accA1 = __builtin_amdgcn_fdot2(bc16(h1.x), bc16(a1), accA1, false);
            accA1 = __builtin_amdgcn_fdot2(bc16(h1.y), bc16(c1), accA1, false);
            accB1 = __builtin_amdgcn_fdot2(bc16(h1.z), bc16(a1), accB1, false);
            accB1 = __builtin_amdgcn_fdot2(bc16(h1.w), bc16(c1), accB1, false);
            j += 2;
        }
        if (j < deg){
            int o0 = __shfl(offv, j, 32);
            uint4 h0 = *(const uint4*)((const char*)h + o0 + boff);
            unsigned a0 = (unsigned)__shfl(wx, j, 32), c0 = (unsigned)__shfl(wy, j, 32);
            accA = __builtin_amdgcn_fdot2(bc16(h0.x), bc16(a0), accA, false);
            accA = __builtin_amdgcn_fdot2(bc16(h0.y), bc16(c0), accA, false);
            accB = __builtin_amdgcn_fdot2(bc16(h0.z), bc16(a0), accB, false);
            accB = __builtin_amdgcn_fdot2(bc16(h0.w), bc16(c0), accB, false);
        }
        accA += accA1; accB += accB1;
    } else {
        float m0 = e0, m1 = e1, m2 = e2, m3 = e3;
        float t0 = v0 ? 1.f : 0.f, t1 = t0, t2 = t0, t3 = t0;
        for (int i = start + 32 + lane32; i < end; i += 32){
            int s = colsrc[i];
            float4 as = *(const float4*)(asrc + (size_t)s * 4);
            float e, nm;
            e = leaky(as.x + ad.x); nm = fmaxf(m0, e); t0 = t0 * __expf(m0 - nm) + __expf(e - nm); m0 = nm;
            e = leaky(as.y + ad.y); nm = fmaxf(m1, e); t1 = t1 * __expf(m1 - nm) + __expf(e - nm); m1 = nm;
            e = leaky(as.z + ad.z); nm = fmaxf(m2, e); t2 = t2 * __expf(m2 - nm) + __expf(e - nm); m2 = nm;
            e = leaky(as.w + ad.w); nm = fmaxf(m3, e); t3 = t3 * __expf(m3 - nm) + __expf(e - nm); m3 = nm;
        }
        #pragma unroll
        for (int off = 1; off < 32; off <<= 1){
            float om, os, nm;
            om = __shfl_xor(m0, off); os = __shfl_xor(t0, off);
            nm = fmaxf(m0, om); t0 = t0 * __expf(m0 - nm) + os * __expf(om - nm); m0 = nm;
            om = __shfl_xor(m1, off); os = __shfl_xor(t1, off);
            nm = fmaxf(m1, om); t1 = t1 * __expf(m1 - nm) + os * __expf(om - nm); m1 = nm;
            om = __shfl_xor(m2, off); os = __shfl_xor(t2, off);
            nm = fmaxf(m2, om); t2 = t2 * __expf(m2 - nm) + os * __expf(om - nm); m2 = nm;
            om = __shfl_xor(m3, off); os = __shfl_xor(t3, off);
            nm = fmaxf(m3, om); t3 = t3 * __expf(m3 - nm) + os * __expf(om - nm); m3 = nm;
        }
        float i0 = 1.f / t0, i1 = 1.f / t1, i2 = 1.f / t2, i3 = 1.f / t3;
        float p0 = __expf(e0 - m0), p1 = __expf(e1 - m1);
        float p2 = __expf(e2 - m2), p3 = __expf(e3 - m3);

        bool first = true;
        for (int base = start; base < end; base += 32){
            int cnt = end - base; if (cnt > 32) cnt = 32;
            float w0, w1, w2, w3; int off = 0;
            if (first){
                w0 = p0 * i0; w1 = p1 * i1; w2 = p2 * i2; w3 = p3 * i3;
                off = v0 ? src0 * (HC * 2) : 0;
            } else {
                w0 = w1 = w2 = w3 = 0.f;
                if (lane32 < cnt){
                    int s = colsrc[base + lane32];
                    float4 as = *(const float4*)(asrc + (size_t)s * 4);
                    w0 = __expf(leaky(as.x + ad.x) - m0) * i0;
                    w1 = __expf(leaky(as.y + ad.y) - m1) * i1;
                    w2 = __expf(leaky(as.z + ad.z) - m2) * i2;
                    w3 = __expf(leaky(as.w + ad.w) - m3) * i3;
                    off = s * (HC * 2);
                }
            }
            first = false;
            half2_t q01 = __builtin_amdgcn_cvt_pkrtz(w0, w1);
            half2_t q23 = __builtin_amdgcn_cvt_pkrtz(w2, w3);
            unsigned wx = __builtin_bit_cast(unsigned, q01);
            unsigned wy = __builtin_bit_cast(unsigned, q23);

            int j = 0;
            for (; j + 2 <= cnt; j += 2){
                int o0 = __shfl(off, j, 32);
                unsigned a0 = __shfl((int)wx, j, 32), b0 = __shfl((int)wy, j, 32);
                int o1 = __shfl(off, j + 1, 32);
                unsigned a1 = __shfl((int)wx, j + 1, 32), b1 = __shfl((int)wy, j + 1, 32);
                uint4 h0 = *(const uint4*)((const char*)h + o0 + boff);
                uint4 h1 = *(const uint4*)((const char*)h + o1 + boff);
                accA = __builtin_amdgcn_fdot2(bc16(h0.x), bc16(a0), accA, false);
                accA = __builtin_amdgcn_fdot2(bc16(h0.y), bc16(b0), accA, false);
                accB = __builtin_amdgcn_fdot2(bc16(h0.z), bc16(a0), accB, false);
                accB = __builtin_amdgcn_fdot2(bc16(h0.w), bc16(b0), accB, false);
                accA = __builtin_amdgcn_fdot2(bc16(h1.x), bc16(a1), accA, false);
                accA = __builtin_amdgcn_fdot2(bc16(h1.y), bc16(b1), accA, false);
                accB = __builtin_amdgcn_fdot2(bc16(h1.z), bc16(a1), accB, false);
                accB = __builtin_amdgcn_fdot2(bc16(h1.w), bc16(b1), accB, false);
            }
            for (; j < cnt; ++j){
                int o0 = __shfl(off, j, 32);
                unsigned a0 = __shfl((int)wx, j, 32), b0 = __shfl((int)wy, j, 32);
                uint4 h0 = *(const uint4*)((const char*)h + o0 + boff);
                accA = __builtin_amdgcn_fdot2(bc16(h0.x), bc16(a0), accA, false);
                accA = __builtin_amdgcn_fdot2(bc16(h0.y), bc16(b0), accA, false);
                accB = __builtin_amdgcn_fdot2(bc16(h0.z), bc16(a0), accB, false);
                accB = __builtin_amdgcn_fdot2(bc16(h0.w), bc16(b0), accB, false);
            }
        }
    }

    float2 bv = *(const float2*)(bias + lane32 * 2);
    float oA = accA * 0.25f + bv.x;
    float oB = accB * 0.25f + bv.y;
    oA = (oA > 0.f) ? oA : expm1f(oA);
    oB = (oB > 0.f) ? oB : expm1f(oB);
    *(float2*)(hout + (size_t)n * CH + lane32 * 2) = make_float2(oA, oB);
}

// ---------------- scorer: MFMA (bf16x3), DIRECT global A reads ----------------

__global__ __launch_bounds__(256) void scorer_mfma_kernel(
    const float* __restrict__ h2, const short* __restrict__ s1hi, const short* __restrict__ s1lo,
    const float* __restrict__ d1p, const float* __restrict__ Ws2, const float* __restrict__ bs2,
    float* __restrict__ out, int N)
{
    constexpr int WP = 72;
    __shared__ short whi[64 * WP];
    __shared__ short wlo[64 * WP];
    const int tid = threadIdx.x;
    const int n0 = blockIdx.x * 64;

    const int wv = tid >> 6, lane = tid & 63;
    const int quad = lane >> 4, ln = lane & 15;
    const int myrow = wv * 16 + ln;
    const int nme = n0 + myrow;

    float fdir[16];
    #pragma unroll
    for (int ks = 0; ks < 2; ++ks){
        float4 f0 = make_float4(0.f, 0.f, 0.f, 0.f), f1 = f0;
        if (nme < N){
            const float* ap = h2 + (size_t)nme * 64 + ks * 32 + quad * 8;
            f0 = *(const float4*)ap;
            f1 = *(const float4*)(ap + 4);
        }
        fdir[ks*8+0]=f0.x; fdir[ks*8+1]=f0.y; fdir[ks*8+2]=f0.z; fdir[ks*8+3]=f0.w;
        fdir[ks*8+4]=f1.x; fdir[ks*8+5]=f1.y; fdir[ks*8+6]=f1.z; fdir[ks*8+7]=f1.w;
    }
    {
        const short8* ghi = (const short8*)s1hi;
        const short8* glo = (const short8*)s1lo;
        short8* lhi = (short8*)whi;
        short8* llo = (short8*)wlo;
        for (int t = tid; t < 64 * WP / 8; t += 256){ lhi[t] = ghi[t]; llo[t] = glo[t]; }
    }
    __syncthreads();

    f32x4 acc[4];
    #pragma unroll
    for (int i = 0; i < 4; ++i) acc[i] = (f32x4){0.f, 0.f, 0.f, 0.f};

    #pragma unroll
    for (int ks = 0; ks < 2; ++ks) {
        const int k0 = ks * 32 + quad * 8;
        short8 ahi, alo;
        #pragma unroll
        for (int e = 0; e < 8; ++e) {
            float v = fdir[ks * 8 + e];
            short hi = bf16_rne(v);
            ahi[e] = hi;
            alo[e] = bf16_rne(v - bf16_to_f(hi));
        }
        #pragma unroll
        for (int nt = 0; nt < 4; ++nt) {
            short8 bhi = *(const short8*)(whi + (nt * 16 + ln) * WP + k0);
            short8 blo = *(const short8*)(wlo + (nt * 16 + ln) * WP + k0);
            acc[nt] = __builtin_amdgcn_mfma_f32_16x16x32_bf16(ahi, bhi, acc[nt], 0, 0, 0);
            acc[nt] = __builtin_amdgcn_mfma_f32_16x16x32_bf16(alo, bhi, acc[nt], 0, 0, 0);
            acc[nt] = __builtin_amdgcn_mfma_f32_16x16x32_bf16(ahi, blo, acc[nt], 0, 0, 0);
        }
    }

    float d1v[4], w2v[4];
    #pragma unroll
    for (int nt = 0; nt < 4; ++nt){
        d1v[nt] = d1p[nt * 16 + ln];
        w2v[nt] = Ws2[nt * 16 + ln];
    }
    float b2 = bs2[0];
    #pragma unroll
    for (int r = 0; r < 4; ++r){
        float t = 0.f;
        #pragma unroll
        for (int nt = 0; nt < 4; ++nt)
            t = fmaf(fmaxf(acc[nt][r] + d1v[nt], 0.f), w2v[nt], t);
        #pragma unroll
        for (int off = 1; off < 16; off <<= 1) t += __shfl_xor(t, off);
        if (ln == 0){
            int n = n0 + wv * 16 + quad * 4 + r;
            if (n < N) out[n] = t + b2;
        }
    }
}

// ---------------- launch ----------------

extern "C" void kernel_launch(void* const* d_in, const int* in_sizes, int n_in,
                              void* d_out, int out_size, void* d_ws, size_t ws_size,
                              hipStream_t stream)
{
    const float* x    = (const float*)d_in[0];
    const int*   ei   = (const int*)  d_in[1];
    const float* donor= (const float*)d_in[2];
    const float* W1   = (const float*)d_in[3];
    const float* as1  = (const float*)d_in[4];
    const float* ad1  = (const float*)d_in[5];
    const float* b1   = (const float*)d_in[6];
    const float* W2   = (const float*)d_in[7];
    const float* as2  = (const float*)d_in[8];
    const float* ad2  = (const float*)d_in[9];
    const float* b2   = (const float*)d_in[10];
    const float* Ws1  = (const float*)d_in[11];
    const float* bs1  = (const float*)d_in[12];
    const float* Ws2  = (const float*)d_in[13];
    const float* bs2  = (const float*)d_in[14];

    const int N  = in_sizes[0] / 27;
    const int E  = in_sizes[1] / 2;
    const int ET = E + N;
    const int NB = (N + 255) / 256;

    char* ws = (char*)d_ws;
    auto alloc = [&](size_t bytes) -> void* {
        void* p = (void*)ws;
        ws += (bytes + 255) / 256 * 256;
        return p;
    };
    int*      rowptr  = (int*)     alloc((size_t)(N + 1) * 4);
    int*      colsrc  = (int*)     alloc((size_t)ET * 4);
    unsigned* pairs   = (unsigned*)alloc((size_t)ET * 4);
    __half*   hbig    = (__half*)  alloc((size_t)N * HC * 2);
    float*    asrc    = (float*)   alloc((size_t)N * 4 * 4);
    float*    adst    = (float*)   alloc((size_t)N * 4 * 4);
    float*    hmid    = (float*)   alloc((size_t)N * CH * 4);
    int*      bucket_cnt    = (int*) alloc(256 * 4);
    int*      bucket_cursor = (int*) alloc(256 * 4);   // contiguous with bucket_cnt
    short*    w1hi    = (short*)   alloc(256 * 40 * 2);
    short*    w2hi    = (short*)   alloc(256 * 72 * 2);
    short*    s1hi    = (short*)   alloc(64 * 72 * 2);
    short*    s1lo    = (short*)   alloc(64 * 72 * 2);
    float*    d1p     = (float*)   alloc(64 * 4);

    const int nblk = (N + 63) / 64;
    const int hblk = (ET + 2047) / 2048;

    (void)hipMemsetAsync(bucket_cnt, 0, 512 * 4, stream);
    prep_hist_kernel<<<256 + hblk, 256, 0, stream>>>(W1, W2, Ws1, bs1, donor,
        w1hi, w2hi, s1hi, s1lo, d1p, ei, E, N, NB, bucket_cnt);
    coarse_scatter_kernel<<<hblk, 256, 0, stream>>>(ei, E, N, NB, bucket_cnt, bucket_cursor, pairs);
    transform1_fine_kernel<<<nblk + NB, 256, 0, stream>>>(
        x, w1hi, as1, ad1, hbig, asrc, adst, N,
        nblk, pairs, bucket_cnt, NB, colsrc, rowptr, ET);
    aggregate_kernel<<<(N + 7) / 8, 256, 0, stream>>>(
        rowptr, colsrc, hbig, asrc, adst, b1, hmid, N);
    transform2_kernel<<<nblk, 256, 0, stream>>>(
        hmid, w2hi, as2, ad2, hbig, asrc, adst, N);
    aggregate_kernel<<<(N + 7) / 8, 256, 0, stream>>>(
        rowptr, colsrc, hbig, asrc, adst, b2, hmid, N);
    scorer_mfma_kernel<<<nblk, 256, 0, stream>>>(
        hmid, s1hi, s1lo, d1p, Ws2, bs2, (float*)d_out, N);
}